// Round 11
// baseline (111.621 us; speedup 1.0000x reference)
//
#include <hip/hip_runtime.h>
#include <cstdint>

#define N_ 4
#define L_ 8192
#define S_ 8192
#define H_ 8
#define D_ 64
#define E_ 64
#define HD_ 512       // H_*D_ row stride in floats
#define NH_ 32        // N_*H_
#define EPS_ 1e-6f
#define TS_ 64        // s-rows per tile (p1)

typedef unsigned int u32;
typedef unsigned short u16;
typedef __attribute__((ext_vector_type(4))) float f32x4;
typedef __attribute__((ext_vector_type(8))) __bf16 bf16x8;

__device__ __forceinline__ float elu1(float x) {
  return x > 0.0f ? x + 1.0f : __expf(x);
}
// f32 pair -> packed bf16x2 (RNE), v_cvt_pk_bf16_f32 (no builtin on gfx950)
__device__ __forceinline__ u32 cvtpk(float a, float b) {
  u32 r;
  asm("v_cvt_pk_bf16_f32 %0, %1, %2" : "=v"(r) : "v"(a), "v"(b));
  return r;
}
__device__ __forceinline__ f32x4 mfma16(bf16x8 a, bf16x8 b, f32x4 c) {
  return __builtin_amdgcn_mfma_f32_16x16x32_bf16(a, b, c, 0, 0, 0);
}

// ---------------- phase 1 (MFMA): partial KV per chunk + partial Ksum -------
// grid (C=32, H, N), block 512 (8 waves). LDS 32 KiB = 2 buf x (K^T 8KB + V^T
// 8KB); row R (a d- or e-index) = 64 bf16 s-values = 128 B exactly (TS=64).
// XOR swizzle ^(((R>>1)&7)<<4) on the byte-in-row for both writes and reads.
// Staging, shuffle-free: threads 0..255 stage K (elu+Ksum), 256..511 stage V.
// Thread (c4=tid&15, sgrp=(tid>>4)&15) loads a 4s x 4d block (4 coalesced
// dwordx4), cvt_pk pairs -> 4 ds_write_b64 (cols c4*4..+3, s-slot sgrp).
// Compute: wave w owns sub-tiles (dd=w&3, ee=2*(w>>2)+{0,1}); per tile:
// 2 A-frag + 4 B-frag ds_read_b128 + 4 MFMA (two k-slabs accumulate).
// One raw barrier per tile; next tile's 4 loads issued pre-barrier stay in
// flight (consuming them at next STAGE gives the counted wait for free).
__global__ __launch_bounds__(512, 8) void p1_kv(const float* __restrict__ keys,
                                                const float* __restrict__ values,
                                                float* __restrict__ pkv,
                                                float* __restrict__ pks,
                                                int tiles) {
  const int chunk = blockIdx.x, h = blockIdx.y, n = blockIdx.z;
  const int tid = threadIdx.x, w = tid >> 6, lane = tid & 63;
  const int m = lane & 15, kb = lane >> 4;
  __shared__ u16 lds[16384];            // 32768 B
  char* base = (char*)lds;

  // ---- staging-side constants ----
  const bool isK = (tid < 256);
  const int c4 = tid & 15;              // d/e col group (cols c4*4..+3)
  const int sgrp = (tid >> 4) & 15;     // s group (rows sgrp*4..+3)
  const int regionOff = isK ? 0 : 8192;
  int wo[4];
  #pragma unroll
  for (int j = 0; j < 4; ++j) {
    const int R = c4 * 4 + j;
    wo[j] = regionOff + R * 128 + ((sgrp * 8) ^ (((R >> 1) & 7) << 4));
  }

  // ---- compute-side constants ----
  const int dd = w & 3, ee0 = (w >> 2) * 2;
  const int Ra = dd * 16 + m;
  const int swA = ((Ra >> 1) & 7) << 4;
  const int aoff0 = Ra * 128 + ((kb * 16) ^ swA);
  const int aoff1 = Ra * 128 + ((64 + kb * 16) ^ swA);
  const int Rb0 = ee0 * 16 + m, Rb1 = Rb0 + 16;
  const int swB0 = ((Rb0 >> 1) & 7) << 4, swB1 = ((Rb1 >> 1) & 7) << 4;
  const int boff00 = 8192 + Rb0 * 128 + ((kb * 16) ^ swB0);
  const int boff01 = 8192 + Rb0 * 128 + ((64 + kb * 16) ^ swB0);
  const int boff10 = 8192 + Rb1 * 128 + ((kb * 16) ^ swB1);
  const int boff11 = 8192 + Rb1 * 128 + ((64 + kb * 16) ^ swB1);

  const float* gsrc = (isK ? keys : values) + (size_t)n * S_ * HD_ + h * D_;
  u32 goff = (u32)((chunk * tiles * TS_ + sgrp * 4) * HD_ + c4 * 4);

  f32x4 acc0 = {0.f, 0.f, 0.f, 0.f}, acc1 = {0.f, 0.f, 0.f, 0.f};
  float4 kss = make_float4(0.f, 0.f, 0.f, 0.f);

  // prologue: tile 0 loads
  float4 r0 = *(const float4*)(gsrc + goff);
  float4 r1 = *(const float4*)(gsrc + goff + HD_);
  float4 r2 = *(const float4*)(gsrc + goff + 2 * HD_);
  float4 r3 = *(const float4*)(gsrc + goff + 3 * HD_);

#define COLW(BUF, j, F0, F1, F2, F3)                                           \
  { u32 lo_ = cvtpk(F0, F1), hi_ = cvtpk(F2, F3);                              \
    *(uint2*)(base + (BUF) + wo[j]) = make_uint2(lo_, hi_); }

  #pragma unroll 1
  for (int t = 0; t < tiles; ++t) {
    const int BUF = (t & 1) * 16384;
    // ---- STAGE tile t (consume r0..r3 -> counted vmcnt wait) ----
    {
      float4 f0 = r0, f1 = r1, f2 = r2, f3 = r3;
      if (isK) {
        f0.x = elu1(f0.x); f0.y = elu1(f0.y); f0.z = elu1(f0.z); f0.w = elu1(f0.w);
        f1.x = elu1(f1.x); f1.y = elu1(f1.y); f1.z = elu1(f1.z); f1.w = elu1(f1.w);
        f2.x = elu1(f2.x); f2.y = elu1(f2.y); f2.z = elu1(f2.z); f2.w = elu1(f2.w);
        f3.x = elu1(f3.x); f3.y = elu1(f3.y); f3.z = elu1(f3.z); f3.w = elu1(f3.w);
        kss.x += f0.x + f1.x + f2.x + f3.x;
        kss.y += f0.y + f1.y + f2.y + f3.y;
        kss.z += f0.z + f1.z + f2.z + f3.z;
        kss.w += f0.w + f1.w + f2.w + f3.w;
      }
      COLW(BUF, 0, f0.x, f1.x, f2.x, f3.x)
      COLW(BUF, 1, f0.y, f1.y, f2.y, f3.y)
      COLW(BUF, 2, f0.z, f1.z, f2.z, f3.z)
      COLW(BUF, 3, f0.w, f1.w, f2.w, f3.w)
    }
    // ---- issue tile t+1 loads (stay in flight across the barrier) ----
    if (t + 1 < tiles) {
      goff += TS_ * HD_;
      r0 = *(const float4*)(gsrc + goff);
      r1 = *(const float4*)(gsrc + goff + HD_);
      r2 = *(const float4*)(gsrc + goff + 2 * HD_);
      r3 = *(const float4*)(gsrc + goff + 3 * HD_);
    }
    // ---- barrier: ds_writes visible; vmem NOT drained ----
    asm volatile("s_waitcnt lgkmcnt(0)" ::: "memory");
    __builtin_amdgcn_s_barrier();
    // ---- COMPUTE tile t: 6 ds_read_b128 + 4 MFMA ----
    {
      uint4 a0r = *(const uint4*)(base + BUF + aoff0);
      uint4 a1r = *(const uint4*)(base + BUF + aoff1);
      uint4 b00 = *(const uint4*)(base + BUF + boff00);
      uint4 b01 = *(const uint4*)(base + BUF + boff01);
      uint4 b10 = *(const uint4*)(base + BUF + boff10);
      uint4 b11 = *(const uint4*)(base + BUF + boff11);
      bf16x8 a0 = __builtin_bit_cast(bf16x8, a0r);
      bf16x8 a1 = __builtin_bit_cast(bf16x8, a1r);
      acc0 = mfma16(a0, __builtin_bit_cast(bf16x8, b00), acc0);
      acc0 = mfma16(a1, __builtin_bit_cast(bf16x8, b01), acc0);
      acc1 = mfma16(a0, __builtin_bit_cast(bf16x8, b10), acc1);
      acc1 = mfma16(a1, __builtin_bit_cast(bf16x8, b11), acc1);
    }
    // single barrier per tile is race-free: STAGE(t+1) targets the other
    // buffer; the barrier separates it from COMPUTE(t+1) readers.
  }
#undef COLW

  // partial KV stores: D[row=4*kb+r][col=m] per sub-tile (m89-verified layout)
  float* pkvb = pkv + ((size_t)chunk * NH_ + (size_t)(n * H_ + h)) * (D_ * E_);
  #pragma unroll
  for (int r = 0; r < 4; ++r) {
    pkvb[(dd * 16 + kb * 4 + r) * 64 + ee0 * 16 + m]       = acc0[r];
    pkvb[(dd * 16 + kb * 4 + r) * 64 + (ee0 + 1) * 16 + m] = acc1[r];
  }

  // partial Ksum block-reduce (reuse LDS as f32 scratch: 16 sgrp x 64 d)
  __syncthreads();
  float* sc = (float*)lds;
  if (isK) *(float4*)(sc + sgrp * 64 + c4 * 4) = kss;
  __syncthreads();
  if (tid < 64) {
    float s = 0.f;
    #pragma unroll
    for (int r = 0; r < 16; ++r) s += sc[r * 64 + tid];
    pks[((size_t)chunk * NH_ + (size_t)(n * H_ + h)) * 64 + tid] = s;
  }
}

// ---------------- reduce: partials -> KVT bf16 [NH][80][64] ------------------
// rows 0..63 = KV^T (e-major, d-contiguous), row 64 = Ksum bf16, 65..79 = 0.
__global__ __launch_bounds__(256) void reduce_kv(const float* __restrict__ pkv,
                                                 const float* __restrict__ pks,
                                                 u16* __restrict__ kvt5, int C) {
  const int nh = blockIdx.x, tid = threadIdx.x;
  __shared__ float lds[64 * 65];
  float acc[16];
  #pragma unroll
  for (int k = 0; k < 16; ++k) acc[k] = 0.f;
  #pragma unroll 1
  for (int c = 0; c < C; ++c) {
    const float* p = pkv + ((size_t)c * NH_ + nh) * 4096;
    #pragma unroll
    for (int j = 0; j < 4; ++j) {
      float4 f = *(const float4*)(p + j * 1024 + tid * 4);
      acc[j * 4 + 0] += f.x; acc[j * 4 + 1] += f.y;
      acc[j * 4 + 2] += f.z; acc[j * 4 + 3] += f.w;
    }
  }
  #pragma unroll
  for (int j = 0; j < 4; ++j)
    #pragma unroll
    for (int k2 = 0; k2 < 4; ++k2)
      lds[(j * 16 + (tid >> 4)) * 65 + (tid & 15) * 4 + k2] = acc[j * 4 + k2];
  __syncthreads();
  {
    const int e = tid >> 2, d0 = (tid & 3) * 16;
    u32 pk8[8];
    #pragma unroll
    for (int q = 0; q < 8; ++q)
      pk8[q] = cvtpk(lds[(d0 + 2 * q) * 65 + e], lds[(d0 + 2 * q + 1) * 65 + e]);
    u16* dst = kvt5 + (size_t)nh * (80 * 64) + e * 64 + d0;
    *(uint4*)(dst)     = make_uint4(pk8[0], pk8[1], pk8[2], pk8[3]);
    *(uint4*)(dst + 8) = make_uint4(pk8[4], pk8[5], pk8[6], pk8[7]);
  }
  if (tid < 64) {
    float s = 0.f;
    #pragma unroll 1
    for (int c = 0; c < C; ++c) s += pks[((size_t)c * NH_ + nh) * 64 + tid];
    kvt5[(size_t)nh * (80 * 64) + 64 * 64 + tid] = (u16)(cvtpk(s, 0.f) & 0xffffu);
  }
  {
    u32* z = (u32*)(kvt5 + (size_t)nh * (80 * 64) + 65 * 64);
    for (int i = tid; i < 480; i += 256) z[i] = 0u;   // 15 rows x 64 bf16
  }
}

// ---------------- phase 2 (MFMA): out = (fQ x KV) * rcp(fQ.Ksum + eps) ------
// grid (64, H, N), block 256 (4 waves). NO LDS, NO barriers. A-frags (fQ)
// built in-register from global (Q rows are d-contiguous); B-frags (KVT +
// Ksum-aux column block) loaded once. 5th ee-block col0 = denominator.
__global__ __launch_bounds__(256, 4) void p2_out(const float* __restrict__ queries,
                                                 const u16* __restrict__ kvt5,
                                                 float* __restrict__ out) {
  const int lt = blockIdx.x, h = blockIdx.y, n = blockIdx.z;
  const int tid = threadIdx.x, w = tid >> 6, lane = tid & 63;
  const int m = lane & 15, kb = lane >> 4;
  const int nh = n * H_ + h;
  const u16* kp = kvt5 + (size_t)nh * (80 * 64);
  uint4 B[5][2];
  #pragma unroll
  for (int ee = 0; ee < 5; ++ee)
    #pragma unroll
    for (int ks = 0; ks < 2; ++ks)
      B[ee][ks] = *(const uint4*)(kp + (ee * 16 + m) * 64 + ks * 32 + kb * 8);

  #pragma unroll 1
  for (int rt = 0; rt < 2; ++rt) {
    const int rowbase = lt * 128 + rt * 64 + w * 16;
    const float* qp = queries + ((size_t)(n * L_ + rowbase + m) * H_ + h) * D_;
    float4 qa = *(const float4*)(qp + kb * 8);
    float4 qb_ = *(const float4*)(qp + kb * 8 + 4);
    float4 qc = *(const float4*)(qp + 32 + kb * 8);
    float4 qd = *(const float4*)(qp + 32 + kb * 8 + 4);
    uint4 a0r, a1r;
    a0r.x = cvtpk(elu1(qa.x), elu1(qa.y));  a0r.y = cvtpk(elu1(qa.z), elu1(qa.w));
    a0r.z = cvtpk(elu1(qb_.x), elu1(qb_.y)); a0r.w = cvtpk(elu1(qb_.z), elu1(qb_.w));
    a1r.x = cvtpk(elu1(qc.x), elu1(qc.y));  a1r.y = cvtpk(elu1(qc.z), elu1(qc.w));
    a1r.z = cvtpk(elu1(qd.x), elu1(qd.y));  a1r.w = cvtpk(elu1(qd.z), elu1(qd.w));
    bf16x8 a0 = __builtin_bit_cast(bf16x8, a0r);
    bf16x8 a1 = __builtin_bit_cast(bf16x8, a1r);
    f32x4 acc[5];
    #pragma unroll
    for (int ee = 0; ee < 5; ++ee) {
      acc[ee] = f32x4{0.f, 0.f, 0.f, 0.f};
      acc[ee] = mfma16(a0, __builtin_bit_cast(bf16x8, B[ee][0]), acc[ee]);
      acc[ee] = mfma16(a1, __builtin_bit_cast(bf16x8, B[ee][1]), acc[ee]);
    }
    float z[4];
    #pragma unroll
    for (int r = 0; r < 4; ++r) {
      float dn = __shfl(acc[4][r], lane & 48, 64);   // col0 of aux block
#if __has_builtin(__builtin_amdgcn_rcpf)
      z[r] = __builtin_amdgcn_rcpf(dn + EPS_);
#else
      z[r] = 1.0f / (dn + EPS_);
#endif
    }
    float* ob = out + ((size_t)(n * L_ + rowbase) * H_ + h) * E_;
    #pragma unroll
    for (int ee = 0; ee < 4; ++ee)
      #pragma unroll
      for (int r = 0; r < 4; ++r)
        ob[(size_t)(kb * 4 + r) * (H_ * E_) + ee * 16 + m] = acc[ee][r] * z[r];
  }
}

extern "C" void kernel_launch(void* const* d_in, const int* in_sizes, int n_in,
                              void* d_out, int out_size, void* d_ws, size_t ws_size,
                              hipStream_t stream) {
  const float* q = (const float*)d_in[0];
  const float* k = (const float*)d_in[1];
  const float* v = (const float*)d_in[2];
  float* outp = (float*)d_out;

  int C = 32;
  while (C > 1) {
    size_t need = ((size_t)C * NH_ * (4096 + 64)) * sizeof(float)
                + (size_t)NH_ * 80 * 64 * sizeof(u16);
    if (need <= ws_size) break;
    C >>= 1;
  }
  float* pkv = (float*)d_ws;                            // C*NH*4096 f32
  float* pks = pkv + (size_t)C * NH_ * 4096;            // C*NH*64 f32
  u16* kvt5 = (u16*)(pks + (size_t)C * NH_ * 64);       // NH*80*64 bf16
  const int tiles = S_ / (C * TS_);                     // 4 at C=32

  hipLaunchKernelGGL(p1_kv, dim3(C, H_, N_), dim3(512), 0, stream, k, v, pkv, pks, tiles);
  hipLaunchKernelGGL(reduce_kv, dim3(NH_), dim3(256), 0, stream, pkv, pks, kvt5, C);
  hipLaunchKernelGGL(p2_out, dim3(L_ / 128, H_, N_), dim3(256), 0, stream, q, kvt5, outp);
}

// Round 12
// 87.129 us; speedup vs baseline: 1.2811x; 1.2811x over previous
//
#include <hip/hip_runtime.h>
#include <cstdint>

#define N_ 4
#define L_ 8192
#define S_ 8192
#define H_ 8
#define D_ 64
#define E_ 64
#define HD_ 512       // H_*D_ row stride in floats
#define NH_ 32        // N_*H_
#define EPS_ 1e-6f
#define TS_ 32        // s-rows per tile (p1)

typedef unsigned int u32;
typedef unsigned short u16;
typedef __attribute__((ext_vector_type(4))) float f32x4;
typedef __attribute__((ext_vector_type(8))) __bf16 bf16x8;

__device__ __forceinline__ float elu1(float x) {
  return x > 0.0f ? x + 1.0f : __expf(x);
}
// f32 pair -> packed bf16x2 (RNE), v_cvt_pk_bf16_f32 (no builtin on gfx950)
__device__ __forceinline__ u32 cvtpk(float a, float b) {
  u32 r;
  asm("v_cvt_pk_bf16_f32 %0, %1, %2" : "=v"(r) : "v"(a), "v"(b));
  return r;
}
__device__ __forceinline__ f32x4 mfma16(bf16x8 a, bf16x8 b, f32x4 c) {
  return __builtin_amdgcn_mfma_f32_16x16x32_bf16(a, b, c, 0, 0, 0);
}

// ---------------- phase 1 (MFMA): partial KV per chunk + partial Ksum -------
// grid (C=32, H, N), block 512 (8 waves). LDS = 2 buf x 64 rows x 128 B
// = 16 KiB. Row R: bytes 0..63 = K^T row (d=R, 16 s-pair u32), bytes 64..127
// = V^T row (e=R). XOR swizzle ^(((R>>1)&7)<<4) on byte-in-row for writes AND
// reads (bijective per row; K/V o-ranges disjoint -> images disjoint).
// Staging role-split, shuffle-free: tid<256 stages K (elu+Ksum), else V.
// Thread (c4=tid&15, a=(tid>>4)&15): 2 coalesced float4 (rows s=2a,2a+1, cols
// c4*4..+3) -> 4 cvt_pk -> 4 ds_write_b32. Only 8 loop-carried prefetch regs
// (R10 proved 8 is spill-free at (512,8); R11's 16 respilled: WRITE 77 MB).
// Compute: wave w owns (dd=w&3, ee=2*(w>>2)+{0,1}); per tile 1 A-frag + 2
// B-frag ds_read_b128 (conflict-free, verified) + 2 MFMA. One raw barrier per
// tile; t+1 loads issued pre-barrier stay in flight (consume = counted wait).
__global__ __launch_bounds__(512, 8) void p1_kv(const float* __restrict__ keys,
                                                const float* __restrict__ values,
                                                float* __restrict__ pkv,
                                                float* __restrict__ pks,
                                                int tiles) {
  const int chunk = blockIdx.x, h = blockIdx.y, n = blockIdx.z;
  const int tid = threadIdx.x, w = tid >> 6, lane = tid & 63;
  const int m = lane & 15, kb = lane >> 4;
  __shared__ u16 lds[2][64 * 64];       // 16384 B
  char* base = (char*)lds;

  // ---- staging-side constants ----
  const bool isK = (tid < 256);
  const int c4 = tid & 15;              // col group (cols c4*4..+3)
  const int a  = (tid >> 4) & 15;       // s-pair index (rows 2a, 2a+1)
  const int vofs = isK ? 0 : 64;
  int wo[4];
  #pragma unroll
  for (int j = 0; j < 4; ++j) {
    const int R = c4 * 4 + j;
    wo[j] = R * 128 + ((vofs + a * 4) ^ (((R >> 1) & 7) << 4));
  }
  const float* gsrc = (isK ? keys : values) + (size_t)n * S_ * HD_ + h * D_;
  u32 goff = (u32)((chunk * tiles * TS_ + 2 * a) * HD_ + c4 * 4);

  // ---- compute-side constants ----
  const int dd = w & 3, ee0 = (w >> 2) * 2;
  const int Ra = dd * 16 + m;
  const int aoff = Ra * 128 + ((kb * 16) ^ (((Ra >> 1) & 7) << 4));
  const int Rb0 = ee0 * 16 + m;
  const int boff0 = Rb0 * 128 + ((64 + kb * 16) ^ (((Rb0 >> 1) & 7) << 4));
  const int boff1 = boff0 + 16 * 128;   // Rb1=Rb0+16: same swizzle bits

  f32x4 acc0 = {0.f, 0.f, 0.f, 0.f}, acc1 = {0.f, 0.f, 0.f, 0.f};
  float4 kss = make_float4(0.f, 0.f, 0.f, 0.f);

  // prologue: tile 0 loads (8 regs)
  float4 r0 = *(const float4*)(gsrc + goff);
  float4 r1 = *(const float4*)(gsrc + goff + HD_);

  #pragma unroll 1
  for (int t = 0; t < tiles; ++t) {
    const int BUF = (t & 1) * 8192;
    // ---- STAGE tile t (consume r0,r1 -> counted vmcnt wait) ----
    {
      float4 f0 = r0, f1 = r1;
      if (isK) {
        f0.x = elu1(f0.x); f0.y = elu1(f0.y); f0.z = elu1(f0.z); f0.w = elu1(f0.w);
        f1.x = elu1(f1.x); f1.y = elu1(f1.y); f1.z = elu1(f1.z); f1.w = elu1(f1.w);
        kss.x += f0.x + f1.x; kss.y += f0.y + f1.y;
        kss.z += f0.z + f1.z; kss.w += f0.w + f1.w;
      }
      *(u32*)(base + BUF + wo[0]) = cvtpk(f0.x, f1.x);
      *(u32*)(base + BUF + wo[1]) = cvtpk(f0.y, f1.y);
      *(u32*)(base + BUF + wo[2]) = cvtpk(f0.z, f1.z);
      *(u32*)(base + BUF + wo[3]) = cvtpk(f0.w, f1.w);
    }
    // ---- issue tile t+1 loads (stay in flight across the barrier) ----
    if (t + 1 < tiles) {
      goff += TS_ * HD_;
      r0 = *(const float4*)(gsrc + goff);
      r1 = *(const float4*)(gsrc + goff + HD_);
    }
    // ---- barrier: ds_writes visible; vmem NOT drained ----
    asm volatile("s_waitcnt lgkmcnt(0)" ::: "memory");
    __builtin_amdgcn_s_barrier();
    // ---- COMPUTE tile t: 3 ds_read_b128 + 2 MFMA ----
    {
      uint4 ar = *(const uint4*)(base + BUF + aoff);
      uint4 b0 = *(const uint4*)(base + BUF + boff0);
      uint4 b1 = *(const uint4*)(base + BUF + boff1);
      bf16x8 av = __builtin_bit_cast(bf16x8, ar);
      acc0 = mfma16(av, __builtin_bit_cast(bf16x8, b0), acc0);
      acc1 = mfma16(av, __builtin_bit_cast(bf16x8, b1), acc1);
    }
    // single barrier/tile race-free: STAGE(t+1) targets the other buffer.
  }

  // partial KV stores: D[row=4*kb+r][col=m] per sub-tile (m89-verified layout)
  float* pkvb = pkv + ((size_t)chunk * NH_ + (size_t)(n * H_ + h)) * (D_ * E_);
  #pragma unroll
  for (int r = 0; r < 4; ++r) {
    pkvb[(dd * 16 + kb * 4 + r) * 64 + ee0 * 16 + m]       = acc0[r];
    pkvb[(dd * 16 + kb * 4 + r) * 64 + (ee0 + 1) * 16 + m] = acc1[r];
  }

  // partial Ksum block-reduce (reuse LDS as f32 scratch: 16 a x 64 d = 4 KB)
  __syncthreads();
  float* sc = (float*)lds;
  if (isK) *(float4*)(sc + a * 64 + c4 * 4) = kss;
  __syncthreads();
  if (tid < 64) {
    float s = 0.f;
    #pragma unroll
    for (int r = 0; r < 16; ++r) s += sc[r * 64 + tid];
    pks[((size_t)chunk * NH_ + (size_t)(n * H_ + h)) * 64 + tid] = s;
  }
}

// ---------------- reduce: partials -> KVT bf16 [NH][80][64] ------------------
// rows 0..63 = KV^T (e-major, d-contiguous), row 64 = Ksum bf16, 65..79 = 0.
__global__ __launch_bounds__(256) void reduce_kv(const float* __restrict__ pkv,
                                                 const float* __restrict__ pks,
                                                 u16* __restrict__ kvt5, int C) {
  const int nh = blockIdx.x, tid = threadIdx.x;
  __shared__ float lds[64 * 65];
  float acc[16];
  #pragma unroll
  for (int k = 0; k < 16; ++k) acc[k] = 0.f;
  #pragma unroll 1
  for (int c = 0; c < C; ++c) {
    const float* p = pkv + ((size_t)c * NH_ + nh) * 4096;
    #pragma unroll
    for (int j = 0; j < 4; ++j) {
      float4 f = *(const float4*)(p + j * 1024 + tid * 4);
      acc[j * 4 + 0] += f.x; acc[j * 4 + 1] += f.y;
      acc[j * 4 + 2] += f.z; acc[j * 4 + 3] += f.w;
    }
  }
  #pragma unroll
  for (int j = 0; j < 4; ++j)
    #pragma unroll
    for (int k2 = 0; k2 < 4; ++k2)
      lds[(j * 16 + (tid >> 4)) * 65 + (tid & 15) * 4 + k2] = acc[j * 4 + k2];
  __syncthreads();
  {
    const int e = tid >> 2, d0 = (tid & 3) * 16;
    u32 pk8[8];
    #pragma unroll
    for (int q = 0; q < 8; ++q)
      pk8[q] = cvtpk(lds[(d0 + 2 * q) * 65 + e], lds[(d0 + 2 * q + 1) * 65 + e]);
    u16* dst = kvt5 + (size_t)nh * (80 * 64) + e * 64 + d0;
    *(uint4*)(dst)     = make_uint4(pk8[0], pk8[1], pk8[2], pk8[3]);
    *(uint4*)(dst + 8) = make_uint4(pk8[4], pk8[5], pk8[6], pk8[7]);
  }
  if (tid < 64) {
    float s = 0.f;
    #pragma unroll 1
    for (int c = 0; c < C; ++c) s += pks[((size_t)c * NH_ + nh) * 64 + tid];
    kvt5[(size_t)nh * (80 * 64) + 64 * 64 + tid] = (u16)(cvtpk(s, 0.f) & 0xffffu);
  }
  {
    u32* z = (u32*)(kvt5 + (size_t)nh * (80 * 64) + 65 * 64);
    for (int i = tid; i < 480; i += 256) z[i] = 0u;   // 15 rows x 64 bf16
  }
}

// ---------------- phase 2 (MFMA): out = (fQ x KV) * rcp(fQ.Ksum + eps) ------
// grid (64, H, N), block 256 (4 waves). NO LDS, NO barriers. A-frags (fQ)
// built in-register from global (Q rows are d-contiguous); B-frags (KVT +
// Ksum-aux column block) loaded once. 5th ee-block col0 = denominator.
__global__ __launch_bounds__(256, 4) void p2_out(const float* __restrict__ queries,
                                                 const u16* __restrict__ kvt5,
                                                 float* __restrict__ out) {
  const int lt = blockIdx.x, h = blockIdx.y, n = blockIdx.z;
  const int tid = threadIdx.x, w = tid >> 6, lane = tid & 63;
  const int m = lane & 15, kb = lane >> 4;
  const int nh = n * H_ + h;
  const u16* kp = kvt5 + (size_t)nh * (80 * 64);
  uint4 B[5][2];
  #pragma unroll
  for (int ee = 0; ee < 5; ++ee)
    #pragma unroll
    for (int ks = 0; ks < 2; ++ks)
      B[ee][ks] = *(const uint4*)(kp + (ee * 16 + m) * 64 + ks * 32 + kb * 8);

  #pragma unroll 1
  for (int rt = 0; rt < 2; ++rt) {
    const int rowbase = lt * 128 + rt * 64 + w * 16;
    const float* qp = queries + ((size_t)(n * L_ + rowbase + m) * H_ + h) * D_;
    float4 qa = *(const float4*)(qp + kb * 8);
    float4 qb_ = *(const float4*)(qp + kb * 8 + 4);
    float4 qc = *(const float4*)(qp + 32 + kb * 8);
    float4 qd = *(const float4*)(qp + 32 + kb * 8 + 4);
    uint4 a0r, a1r;
    a0r.x = cvtpk(elu1(qa.x), elu1(qa.y));  a0r.y = cvtpk(elu1(qa.z), elu1(qa.w));
    a0r.z = cvtpk(elu1(qb_.x), elu1(qb_.y)); a0r.w = cvtpk(elu1(qb_.z), elu1(qb_.w));
    a1r.x = cvtpk(elu1(qc.x), elu1(qc.y));  a1r.y = cvtpk(elu1(qc.z), elu1(qc.w));
    a1r.z = cvtpk(elu1(qd.x), elu1(qd.y));  a1r.w = cvtpk(elu1(qd.z), elu1(qd.w));
    bf16x8 a0 = __builtin_bit_cast(bf16x8, a0r);
    bf16x8 a1 = __builtin_bit_cast(bf16x8, a1r);
    f32x4 acc[5];
    #pragma unroll
    for (int ee = 0; ee < 5; ++ee) {
      acc[ee] = f32x4{0.f, 0.f, 0.f, 0.f};
      acc[ee] = mfma16(a0, __builtin_bit_cast(bf16x8, B[ee][0]), acc[ee]);
      acc[ee] = mfma16(a1, __builtin_bit_cast(bf16x8, B[ee][1]), acc[ee]);
    }
    float z[4];
    #pragma unroll
    for (int r = 0; r < 4; ++r) {
      float dn = __shfl(acc[4][r], lane & 48, 64);   // col0 of aux block
#if __has_builtin(__builtin_amdgcn_rcpf)
      z[r] = __builtin_amdgcn_rcpf(dn + EPS_);
#else
      z[r] = 1.0f / (dn + EPS_);
#endif
    }
    float* ob = out + ((size_t)(n * L_ + rowbase) * H_ + h) * E_;
    #pragma unroll
    for (int ee = 0; ee < 4; ++ee)
      #pragma unroll
      for (int r = 0; r < 4; ++r)
        ob[(size_t)(kb * 4 + r) * (H_ * E_) + ee * 16 + m] = acc[ee][r] * z[r];
  }
}

extern "C" void kernel_launch(void* const* d_in, const int* in_sizes, int n_in,
                              void* d_out, int out_size, void* d_ws, size_t ws_size,
                              hipStream_t stream) {
  const float* q = (const float*)d_in[0];
  const float* k = (const float*)d_in[1];
  const float* v = (const float*)d_in[2];
  float* outp = (float*)d_out;

  int C = 32;
  while (C > 1) {
    size_t need = ((size_t)C * NH_ * (4096 + 64)) * sizeof(float)
                + (size_t)NH_ * 80 * 64 * sizeof(u16);
    if (need <= ws_size) break;
    C >>= 1;
  }
  float* pkv = (float*)d_ws;                            // C*NH*4096 f32
  float* pks = pkv + (size_t)C * NH_ * 4096;            // C*NH*64 f32
  u16* kvt5 = (u16*)(pks + (size_t)C * NH_ * 64);       // NH*80*64 bf16
  const int tiles = S_ / (C * TS_);                     // 8 at C=32

  hipLaunchKernelGGL(p1_kv, dim3(C, H_, N_), dim3(512), 0, stream, k, v, pkv, pks, tiles);
  hipLaunchKernelGGL(reduce_kv, dim3(NH_), dim3(256), 0, stream, pkv, pks, kvt5, C);
  hipLaunchKernelGGL(p2_out, dim3(L_ / 128, H_, N_), dim3(256), 0, stream, q, kvt5, outp);
}